// Round 6
// baseline (255.165 us; speedup 1.0000x reference)
//
#include <hip/hip_runtime.h>

// SimpleEncoder: LSTM(B=4096, S=512, I=3, H=16) + Linear(16->5) + clip(+-10)
//
// R6: 32 lanes/batch -> 2048 waves -> 2 waves/SIMD (fills chain stalls that
// dominate at 1 wave/SIMD). Per 32-lane group: lanes 0-15 (row A) own gates
// {i,f} of unit j, lanes 16-31 (row B) own {g,o}. All pk_fma operands are
// natural k-pairs {h[2k],h[2k+1]} x {w[2k],w[2k+1]} -> no splat v_movs.
// After activations one ds_swizzle xor16 pair exchanges gate values; BOTH
// rows compute the identical c/h update (free under SIMT), so h stays
// replicated and DPP row_newbcast works per 16-row. waves_per_eu(2,2) gives
// a 256-VGPR budget (R3's VGPR_Count=52 showed it was spilling).
// x staged through LDS in 64-step double-buffered chunks, intra-wave, no
// barriers; ds_read_b128 prefetched 2 steps ahead.

#define TS 512
#define LOG2E 1.44269504088896340736f

typedef float f32x2 __attribute__((ext_vector_type(2)));

// DPP row_newbcast:K — broadcast lane K of each 16-lane row to the whole row.
#define BC(K) __int_as_float(__builtin_amdgcn_update_dpp(0, hvi, 0x150 + (K), 0xf, 0xf, true))
#define BCAST_ALL() \
  hb2[0] = f32x2{BC(0),  BC(1)};  hb2[1] = f32x2{BC(2),  BC(3)}; \
  hb2[2] = f32x2{BC(4),  BC(5)};  hb2[3] = f32x2{BC(6),  BC(7)}; \
  hb2[4] = f32x2{BC(8),  BC(9)};  hb2[5] = f32x2{BC(10), BC(11)}; \
  hb2[6] = f32x2{BC(12), BC(13)}; hb2[7] = f32x2{BC(14), BC(15)}

// ds_swizzle BitMode xor16: lane l <-> lane l^16 within each 32-lane group.
#define SWZ16(v) __int_as_float(__builtin_amdgcn_ds_swizzle(__float_as_int(v), 0x401F))

__global__ __launch_bounds__(256)
__attribute__((amdgpu_waves_per_eu(2, 2)))
void lstm_enc_kernel(const float* __restrict__ x,
                     const float* __restrict__ W_ih,
                     const float* __restrict__ W_hh,
                     const float* __restrict__ b_ih,
                     const float* __restrict__ b_hh,
                     const float* __restrict__ W_lin,
                     const float* __restrict__ b_lin,
                     float* __restrict__ out) {
  const int tid = threadIdx.x;
  const int m = tid & 31;                        // lane within batch group
  const int j = m & 15;                          // hidden unit owned
  const bool rowB = (m & 16) != 0;               // row A: {i,f}; row B: {g,o}
  const int g = tid >> 5;                        // batch slot in block (0..7)
  const int batch = blockIdx.x * 8 + g;
  const int jo = (j < 5) ? j : 0;                // clamped row for W_lin loads

  // x staging: xs[parity][step-in-chunk][slot] as float4 {x0,x1,x2,pad}
  __shared__ float4 xs[2][64][8];
  float4* xsf = &xs[0][0][0];                    // idx = (s&127)*8 + g

  // gate rows + activation scale folding:
  //  i,f,o: z = -log2e * preact  -> sigmoid = rcp(1+exp2(z))
  //  g:     z = +2log2e * preact -> sg = rcp(1+exp2(z)), tanh = 1-2*sg
  const int gA = rowB ? j + 32 : j;              // g : i
  const int gB = rowB ? j + 48 : j + 16;         // o : f
  const float sA = rowB ? 2.0f * LOG2E : -LOG2E;
  const float sB = -LOG2E;

  // weights packed over k-pairs (natural f32x2 operands, no splats)
  f32x2 wA[8], wB[8], wl2[8];
#pragma unroll
  for (int k = 0; k < 8; ++k) {
    wA[k]  = f32x2{W_hh[gA * 16 + 2 * k] * sA, W_hh[gA * 16 + 2 * k + 1] * sA};
    wB[k]  = f32x2{W_hh[gB * 16 + 2 * k] * sB, W_hh[gB * 16 + 2 * k + 1] * sB};
    wl2[k] = f32x2{W_lin[jo * 16 + 2 * k],     W_lin[jo * 16 + 2 * k + 1]};
  }
  const f32x2 xwA01 = f32x2{W_ih[gA * 3 + 0] * sA, W_ih[gA * 3 + 1] * sA};
  const f32x2 xwB01 = f32x2{W_ih[gB * 3 + 0] * sB, W_ih[gB * 3 + 1] * sB};
  const float xwA2 = W_ih[gA * 3 + 2] * sA;
  const float xwB2 = W_ih[gB * 3 + 2] * sB;
  const float bA = (b_ih[gA] + b_hh[gA]) * sA;
  const float bB = (b_ih[gB] + b_hh[gB]) * sB;
  const float bl = b_lin[jo];

  const float* __restrict__ xb = x + (size_t)batch * (TS * 3);
  float* __restrict__ ob = out + (size_t)batch * (TS * 5) + j;
  const bool storer = (m < 5);                   // row A lanes 0..4 store

  // ---- staging (intra-wave): lane m stages steps {2m,2m+1} of each chunk
  // (floats 6m..6m+5; 24m-byte offset is 8-aligned -> three f32x2 loads)
  const float* xc0 = xb + m * 6;                 // + chunk*192 floats
  f32x2 d0, d1, d2;                              // 6 staged floats in flight

  // prologue: stage chunk 0, start loads for chunk 1
  d0 = *(const f32x2*)(xc0 + 0);
  d1 = *(const f32x2*)(xc0 + 2);
  d2 = *(const f32x2*)(xc0 + 4);
  {
    const int wb = (2 * m) * 8 + g;              // parity 0
    xsf[wb]     = float4{d0.x, d0.y, d1.x, 0.f};
    xsf[wb + 8] = float4{d1.y, d2.x, d2.y, 0.f};
  }
  d0 = *(const f32x2*)(xc0 + 192 + 0);
  d1 = *(const f32x2*)(xc0 + 192 + 2);
  d2 = *(const f32x2*)(xc0 + 192 + 4);

  // prefetch x for steps 0 and 1
  float4 xr[2];
  xr[0] = xsf[0 * 8 + g];
  xr[1] = xsf[1 * 8 + g];

  float h = 0.0f, c = 0.0f;

  auto step = [&](int s, int slot) {
    const float4 xt = xr[slot];
    // issue ds_read for step s+2 into the slot just freed
    xr[slot] = xsf[(((s + 2) & 127) << 3) + g];

    // broadcast h_{t-1} across each 16-lane row (DPP, VALU pipe)
    f32x2 hb2[8];
    const int hvi = __float_as_int(h);
    BCAST_ALL();

    // gate pre-activations + output projection, all pk over k-pairs
    f32x2 accA = f32x2{bA, 0.f};
    f32x2 accB = f32x2{bB, 0.f};
    f32x2 accO = f32x2{bl, 0.f};
    const f32x2 x01 = f32x2{xt.x, xt.y};
    accA = x01 * xwA01 + accA;
    accB = x01 * xwB01 + accB;
#pragma unroll
    for (int k = 0; k < 8; ++k) {
      accA = hb2[k] * wA[k] + accA;
      accB = hb2[k] * wB[k] + accB;
      accO = hb2[k] * wl2[k] + accO;
    }
    const float zA = fmaf(xt.z, xwA2, accA.x + accA.y);
    const float zB = fmaf(xt.z, xwB2, accB.x + accB.y);

    // output projection W_lin . h_{t-1} -> out[s-1]
    if (s > 0 && storer) {
      const float oa = accO.x + accO.y;
      ob[(s - 1) * 5] = fminf(fmaxf(oa, -10.0f), 10.0f);
    }

    // uniform activation: r = rcp(1 + exp2(z))
    const float r0 = __builtin_amdgcn_rcpf(1.0f + __builtin_amdgcn_exp2f(zA));
    const float r1 = __builtin_amdgcn_rcpf(1.0f + __builtin_amdgcn_exp2f(zB));

    // exchange across rows: row A has {ig,fg}=r0,r1; row B has {sg,og}=r0,r1
    const float q0 = SWZ16(r0);
    const float q1 = SWZ16(r1);
    const float ig = rowB ? q0 : r0;
    const float fg = rowB ? q1 : r1;
    const float sg = rowB ? r0 : q0;
    const float og = rowB ? r1 : q1;

    // both rows compute the identical c,h update (keeps h in all 32 lanes)
    const float gg = fmaf(-2.0f, sg, 1.0f);      // tanh(g)
    c = fmaf(fg, c, ig * gg);
    const float tc = fmaf(-2.0f,
        __builtin_amdgcn_rcpf(1.0f + __builtin_amdgcn_exp2f((2.0f * LOG2E) * c)), 1.0f);
    h = og * tc;
  };

  for (int ch = 0; ch < 8; ++ch) {
    const int base = ch * 64;

    // first half of the chunk
#pragma unroll 2
    for (int u = 0; u < 32; ++u) step(base + u, u & 1);

    // mid-chunk: stage chunk ch+1 (regs loaded ~64 steps ago), start ch+2 loads
    if (ch < 7) {
      const int p = (ch + 1) & 1;
      const int wb = (p * 64 + 2 * m) * 8 + g;
      xsf[wb]     = float4{d0.x, d0.y, d1.x, 0.f};
      xsf[wb + 8] = float4{d1.y, d2.x, d2.y, 0.f};
    }
    if (ch < 6) {
      const float* xc = xc0 + (ch + 2) * 192;
      d0 = *(const f32x2*)(xc + 0);
      d1 = *(const f32x2*)(xc + 2);
      d2 = *(const f32x2*)(xc + 4);
    }

    // second half of the chunk
#pragma unroll 2
    for (int u = 32; u < 64; ++u) step(base + u, u & 1);
  }

  // final timestep's output (uses h_{S-1})
  {
    f32x2 hb2[8];
    const int hvi = __float_as_int(h);
    BCAST_ALL();
    f32x2 accO = f32x2{bl, 0.f};
#pragma unroll
    for (int k = 0; k < 8; ++k) accO = hb2[k] * wl2[k] + accO;
    const float oa = accO.x + accO.y;
    if (storer) {
      ob[(TS - 1) * 5] = fminf(fmaxf(oa, -10.0f), 10.0f);
    }
  }
}

extern "C" void kernel_launch(void* const* d_in, const int* in_sizes, int n_in,
                              void* d_out, int out_size, void* d_ws, size_t ws_size,
                              hipStream_t stream) {
  const float* x     = (const float*)d_in[0];
  const float* W_ih  = (const float*)d_in[1];
  const float* W_hh  = (const float*)d_in[2];
  const float* b_ih  = (const float*)d_in[3];
  const float* b_hh  = (const float*)d_in[4];
  const float* W_lin = (const float*)d_in[5];
  const float* b_lin = (const float*)d_in[6];
  float* out = (float*)d_out;

  const int B = in_sizes[0] / (TS * 3);   // 4096
  const int grid = B / 8;                 // 8 batch elements per 256-thread block
  lstm_enc_kernel<<<grid, 256, 0, stream>>>(x, W_ih, W_hh, b_ih, b_hh, W_lin, b_lin, out);
}